// Round 1
// baseline (3301.789 us; speedup 1.0000x reference)
//
#include <hip/hip_runtime.h>

#define NN 50000
#define NE 800000
#define D 64

// Accumulate h[j] += (x[k]*scale) * W[k*64+j] for k=0..63.
// x is per-lane (divergent); W rows are uniform-address -> scalar loads.
__device__ __forceinline__ void mlp_accum64(const float* __restrict__ x,
                                            const float* __restrict__ W,
                                            float scale, float* h) {
    const float4* x4 = (const float4*)x;
    #pragma unroll 1
    for (int k0 = 0; k0 < D; k0 += 8) {
        float xa[8];
        float4 v0 = x4[k0 / 4];
        float4 v1 = x4[k0 / 4 + 1];
        xa[0] = v0.x; xa[1] = v0.y; xa[2] = v0.z; xa[3] = v0.w;
        xa[4] = v1.x; xa[5] = v1.y; xa[6] = v1.z; xa[7] = v1.w;
        #pragma unroll
        for (int kk = 0; kk < 8; ++kk) {
            const float xk = xa[kk] * scale;
            const float* Wr = W + (k0 + kk) * D;
            #pragma unroll
            for (int j = 0; j < D; ++j) h[j] = fmaf(xk, Wr[j], h[j]);
        }
    }
}

// acc[j] = b2[j] + sum_k relu(h[k]) * W2[k*64+j]
// Dynamic h[k] index goes through a per-lane private LDS row (stride 33
// floats: (l*33+k)%32 covers all banks at 2-way aliasing = free; no barriers
// needed since each lane touches only its own row).
__device__ __forceinline__ void mlp_layer2(const float* __restrict__ W2,
                                           const float* __restrict__ b2,
                                           const float* h, float* acc,
                                           float* myrow) {
    #pragma unroll
    for (int j = 0; j < D; ++j) acc[j] = b2[j];
    #pragma unroll
    for (int half = 0; half < 2; ++half) {
        #pragma unroll
        for (int k = 0; k < 32; ++k) myrow[k] = fmaxf(h[half * 32 + k], 0.f);
        #pragma unroll 1
        for (int k = 0; k < 32; ++k) {
            const float hk = myrow[k];
            const float* Wr = W2 + (half * 32 + k) * D;
            #pragma unroll
            for (int j = 0; j < D; ++j) acc[j] = fmaf(hk, Wr[j], acc[j]);
        }
    }
}

__global__ __launch_bounds__(256) void edge_kernel(
    const float* __restrict__ feats, const int* __restrict__ ei,
    const float* __restrict__ ea, const float* __restrict__ W1,
    const float* __restrict__ b1, const float* __restrict__ W2,
    const float* __restrict__ b2, float* __restrict__ e_out,
    float* __restrict__ agg, float* __restrict__ deg) {
    __shared__ float sh[256 * 33];
    const int tid = threadIdx.x;
    const int eid = blockIdx.x * 256 + tid;  // grid*block == NE exactly

    const int2 rc = ((const int2*)ei)[eid];
    const int r = rc.x;
    const int c = rc.y;

    float h[D];
    #pragma unroll
    for (int j = 0; j < D; ++j) h[j] = b1[j];

    const float* xr = feats + (size_t)r * D;
    const float* xc = feats + (size_t)c * D;
    const float* xe = ea + (size_t)eid * D;

    #pragma unroll 1
    for (int s = 0; s < 3; ++s) {
        const float* xp = (s == 0) ? xr : ((s == 1) ? xc : xe);
        mlp_accum64(xp, W1 + s * D * D, 1.0f, h);
    }

    float acc[D];
    mlp_layer2(W2, b2, h, acc, sh + tid * 33);

    // write e row (dense across the wave: 64 consecutive rows)
    float4* eo4 = (float4*)(e_out + (size_t)eid * D);
    #pragma unroll
    for (int q = 0; q < 16; ++q)
        eo4[q] = make_float4(acc[4 * q + 0], acc[4 * q + 1],
                             acc[4 * q + 2], acc[4 * q + 3]);

    // scatter-add into agg[c] + degree count
    float* ag = agg + (size_t)c * D;
    #pragma unroll
    for (int j = 0; j < D; ++j) unsafeAtomicAdd(ag + j, acc[j]);
    unsafeAtomicAdd(deg + c, 1.0f);
}

__global__ __launch_bounds__(64) void node_kernel(
    const float* __restrict__ feats, const float* __restrict__ agg,
    const float* __restrict__ deg, const float* __restrict__ W1,
    const float* __restrict__ b1, const float* __restrict__ W2,
    const float* __restrict__ b2, float* __restrict__ out) {
    __shared__ float sh[64 * 33];
    const int tid = threadIdx.x;
    const int n = blockIdx.x * 64 + tid;
    if (n >= NN) return;

    float h[D];
    #pragma unroll
    for (int j = 0; j < D; ++j) h[j] = b1[j];

    const float rd = 1.0f / fmaxf(deg[n], 1.0f);

    mlp_accum64(feats + (size_t)n * D, W1, 1.0f, h);
    mlp_accum64(agg + (size_t)n * D, W1 + D * D, rd, h);

    float acc[D];
    mlp_layer2(W2, b2, h, acc, sh + tid * 33);

    float4* o4 = (float4*)(out + (size_t)n * D);
    #pragma unroll
    for (int q = 0; q < 16; ++q)
        o4[q] = make_float4(acc[4 * q + 0], acc[4 * q + 1],
                            acc[4 * q + 2], acc[4 * q + 3]);
}

extern "C" void kernel_launch(void* const* d_in, const int* in_sizes, int n_in,
                              void* d_out, int out_size, void* d_ws,
                              size_t ws_size, hipStream_t stream) {
    const float* feats = (const float*)d_in[0];
    const int* ei      = (const int*)d_in[1];
    const float* ea    = (const float*)d_in[2];
    const float* W1e   = (const float*)d_in[3];
    const float* b1e   = (const float*)d_in[4];
    const float* W2e   = (const float*)d_in[5];
    const float* b2e   = (const float*)d_in[6];
    const float* W1n   = (const float*)d_in[7];
    const float* b1n   = (const float*)d_in[8];
    const float* W2n   = (const float*)d_in[9];
    const float* b2n   = (const float*)d_in[10];

    float* out_f = (float*)d_out;
    float* feats_out = out_f;                       // NN*D
    float* e_out = out_f + (size_t)NN * D;          // NE*D

    float* agg = (float*)d_ws;                      // NN*D
    float* deg = agg + (size_t)NN * D;              // NN

    hipMemsetAsync(d_ws, 0, ((size_t)NN * D + NN) * sizeof(float), stream);

    edge_kernel<<<NE / 256, 256, 0, stream>>>(feats, ei, ea, W1e, b1e, W2e,
                                              b2e, e_out, agg, deg);
    node_kernel<<<(NN + 63) / 64, 64, 0, stream>>>(feats, agg, deg, W1n, b1n,
                                                   W2n, b2n, feats_out);
}

// Round 2
// 920.964 us; speedup vs baseline: 3.5851x; 3.5851x over previous
//
#include <hip/hip_runtime.h>

#define NN 50000
#define NE 800000
#define D 64

// Accumulate h[j] += (x[k]*scale) * W[k*64+j] for k=0..63.
// x is per-lane (divergent); W rows are uniform-address -> scalar loads.
__device__ __forceinline__ void mlp_accum64(const float* __restrict__ x,
                                            const float* __restrict__ W,
                                            float scale, float* h) {
    const float4* x4 = (const float4*)x;
    #pragma unroll 1
    for (int k0 = 0; k0 < D; k0 += 8) {
        float xa[8];
        float4 v0 = x4[k0 / 4];
        float4 v1 = x4[k0 / 4 + 1];
        xa[0] = v0.x; xa[1] = v0.y; xa[2] = v0.z; xa[3] = v0.w;
        xa[4] = v1.x; xa[5] = v1.y; xa[6] = v1.z; xa[7] = v1.w;
        #pragma unroll
        for (int kk = 0; kk < 8; ++kk) {
            const float xk = xa[kk] * scale;
            const float* Wr = W + (k0 + kk) * D;
            #pragma unroll
            for (int j = 0; j < D; ++j) h[j] = fmaf(xk, Wr[j], h[j]);
        }
    }
}

// acc[j] = b2[j] + sum_k relu(h[k]) * W2[k*64+j]
// Dynamic h[k] goes through a per-lane private LDS row (stride 33 floats:
// (l*33+k)%32 spans banks at 2-way aliasing = free; wave-private, no barriers).
__device__ __forceinline__ void mlp_layer2(const float* __restrict__ W2,
                                           const float* __restrict__ b2,
                                           const float* h, float* acc,
                                           float* myrow) {
    #pragma unroll
    for (int j = 0; j < D; ++j) acc[j] = b2[j];
    #pragma unroll
    for (int half = 0; half < 2; ++half) {
        #pragma unroll
        for (int k = 0; k < 32; ++k) myrow[k] = fmaxf(h[half * 32 + k], 0.f);
        #pragma unroll 1
        for (int k = 0; k < 32; ++k) {
            const float hk = myrow[k];
            const float* Wr = W2 + (half * 32 + k) * D;
            #pragma unroll
            for (int j = 0; j < D; ++j) acc[j] = fmaf(hk, Wr[j], acc[j]);
        }
    }
}

__global__ __launch_bounds__(256) void edge_kernel(
    const float* __restrict__ feats, const int* __restrict__ ei,
    const float* __restrict__ ea, const float* __restrict__ W1,
    const float* __restrict__ b1, const float* __restrict__ W2,
    const float* __restrict__ b2, float* __restrict__ e_out,
    float* __restrict__ agg, float* __restrict__ deg) {
    __shared__ float myrow_s[256 * 33];   // 33792 B
    __shared__ float tbuf[4][64 * 17];    // 17408 B — wave-private transpose tile
    __shared__ int cbuf[4][64];           // 1024 B  — dest node per edge
    const int tid = threadIdx.x;
    const int w = tid >> 6;
    const int lane = tid & 63;
    const int eid = blockIdx.x * 256 + tid;       // grid*block == NE exactly
    const int ebase = blockIdx.x * 256 + w * 64;  // first edge of this wave

    const int2 rc = ((const int2*)ei)[eid];
    const int r = rc.x;
    const int c = rc.y;

    float h[D];
    #pragma unroll
    for (int j = 0; j < D; ++j) h[j] = b1[j];

    const float* xr = feats + (size_t)r * D;
    const float* xc = feats + (size_t)c * D;
    const float* xe = ea + (size_t)eid * D;

    #pragma unroll 1
    for (int s = 0; s < 3; ++s) {
        const float* xp = (s == 0) ? xr : ((s == 1) ? xc : xe);
        mlp_accum64(xp, W1 + s * D * D, 1.0f, h);
    }

    float acc[D];
    mlp_layer2(W2, b2, h, acc, myrow_s + tid * 33);

    // --- transposed, line-coalesced emission of e_out + agg atomics ---
    // Wave-private tile; wave-synchronous LDS (no barriers needed).
    cbuf[w][lane] = c;
    float* T = tbuf[w];
    const int es = lane >> 4;   // edge subgroup 0..3
    const int js = lane & 15;   // column within 16-wide chunk
    #pragma unroll 1
    for (int c0 = 0; c0 < D; c0 += 16) {
        #pragma unroll
        for (int i = 0; i < 16; ++i) T[lane * 17 + i] = acc[c0 + i];
        #pragma unroll 1
        for (int g = 0; g < 16; ++g) {
            const int o = g * 4 + es;                 // edge slot in wave
            const float v = T[o * 17 + js];
            const int cd = cbuf[w][o];                // broadcast read
            e_out[(size_t)(ebase + o) * D + c0 + js] = v;      // 4 full lines/instr
            unsafeAtomicAdd(agg + (size_t)cd * D + c0 + js, v); // 4 full lines/instr
        }
    }
    unsafeAtomicAdd(deg + c, 1.0f);
}

__global__ __launch_bounds__(64) void node_kernel(
    const float* __restrict__ feats, const float* __restrict__ agg,
    const float* __restrict__ deg, const float* __restrict__ W1,
    const float* __restrict__ b1, const float* __restrict__ W2,
    const float* __restrict__ b2, float* __restrict__ out) {
    __shared__ float sh[64 * 33];
    const int tid = threadIdx.x;
    const int n = blockIdx.x * 64 + tid;
    if (n >= NN) return;

    float h[D];
    #pragma unroll
    for (int j = 0; j < D; ++j) h[j] = b1[j];

    const float rd = 1.0f / fmaxf(deg[n], 1.0f);

    mlp_accum64(feats + (size_t)n * D, W1, 1.0f, h);
    mlp_accum64(agg + (size_t)n * D, W1 + D * D, rd, h);

    float acc[D];
    mlp_layer2(W2, b2, h, acc, sh + tid * 33);

    float4* o4 = (float4*)(out + (size_t)n * D);
    #pragma unroll
    for (int q = 0; q < 16; ++q)
        o4[q] = make_float4(acc[4 * q + 0], acc[4 * q + 1],
                            acc[4 * q + 2], acc[4 * q + 3]);
}

extern "C" void kernel_launch(void* const* d_in, const int* in_sizes, int n_in,
                              void* d_out, int out_size, void* d_ws,
                              size_t ws_size, hipStream_t stream) {
    const float* feats = (const float*)d_in[0];
    const int* ei      = (const int*)d_in[1];
    const float* ea    = (const float*)d_in[2];
    const float* W1e   = (const float*)d_in[3];
    const float* b1e   = (const float*)d_in[4];
    const float* W2e   = (const float*)d_in[5];
    const float* b2e   = (const float*)d_in[6];
    const float* W1n   = (const float*)d_in[7];
    const float* b1n   = (const float*)d_in[8];
    const float* W2n   = (const float*)d_in[9];
    const float* b2n   = (const float*)d_in[10];

    float* out_f = (float*)d_out;
    float* feats_out = out_f;                  // NN*D
    float* e_out = out_f + (size_t)NN * D;     // NE*D

    float* agg = (float*)d_ws;                 // NN*D
    float* deg = agg + (size_t)NN * D;         // NN

    hipMemsetAsync(d_ws, 0, ((size_t)NN * D + NN) * sizeof(float), stream);

    edge_kernel<<<NE / 256, 256, 0, stream>>>(feats, ei, ea, W1e, b1e, W2e,
                                              b2e, e_out, agg, deg);
    node_kernel<<<(NN + 63) / 64, 64, 0, stream>>>(feats, agg, deg, W1n, b1n,
                                                   W2n, b2n, feats_out);
}